// Round 1
// baseline (852.487 us; speedup 1.0000x reference)
//
#include <hip/hip_runtime.h>
#include <math.h>

// Fused spectral Wirtinger-derivative kernel.
// One 1024-thread block per (b,C) image; whole 128x128 complex image in LDS.
// Each 128-point FFT: 8 threads x 16 register points, 16x8 Cooley-Tukey,
// single LDS exchange per 1-D transform. XOR-swizzled exchange slots keep
// LDS bank conflicts <=2-way (free on gfx950).

#define LSTR 132                 // LDS row stride in floats (+4 pad: 2-way banks)
#define SHBYTES (2 * 128 * LSTR * 4)

struct cf { float re, im; };
__device__ __forceinline__ cf cmul(cf a, cf b) {
    return { a.re * b.re - a.im * b.im, a.re * b.im + a.im * b.re };
}
__device__ __forceinline__ cf cadd(cf a, cf b) { return { a.re + b.re, a.im + b.im }; }
__device__ __forceinline__ cf csub(cf a, cf b) { return { a.re - b.re, a.im - b.im }; }

// bit-reversal tables (involutions)
__device__ constexpr int BR4[16] = {0,8,4,12,2,10,6,14,1,9,5,13,3,11,7,15};
__device__ constexpr int BR3[8]  = {0,4,2,6,1,5,3,7};

// 16-point DFT, radix-2 DIF, natural in, bit-reversed out: R[k] = r[BR4[k]].
// R[k] = sum_j r[j] e^{SGN*2pi i jk/16}
template <int SGN>
__device__ __forceinline__ void dft16(cf* r) {
    const float C16[8] = {1.f, 0.92387953251f, 0.70710678119f, 0.38268343236f,
                          0.f, -0.38268343236f, -0.70710678119f, -0.92387953251f};
    const float S16[8] = {0.f, 0.38268343236f, 0.70710678119f, 0.92387953251f,
                          1.f, 0.92387953251f, 0.70710678119f, 0.38268343236f};
    const float C8[4] = {1.f, 0.70710678119f, 0.f, -0.70710678119f};
    const float S8[4] = {0.f, 0.70710678119f, 1.f, 0.70710678119f};
#pragma unroll
    for (int j = 0; j < 8; j++) {
        cf u = r[j], v = r[j + 8];
        r[j] = cadd(u, v);
        cf d = csub(u, v);
        cf w = { C16[j], (float)SGN * S16[j] };
        r[j + 8] = cmul(d, w);
    }
#pragma unroll
    for (int b = 0; b < 16; b += 8)
#pragma unroll
        for (int j = 0; j < 4; j++) {
            cf u = r[b + j], v = r[b + j + 4];
            r[b + j] = cadd(u, v);
            cf d = csub(u, v);
            cf w = { C8[j], (float)SGN * S8[j] };
            r[b + j + 4] = cmul(d, w);
        }
#pragma unroll
    for (int b = 0; b < 16; b += 4) {
        cf u = r[b], v = r[b + 2];
        r[b] = cadd(u, v); r[b + 2] = csub(u, v);
        u = r[b + 1]; v = r[b + 3];
        r[b + 1] = cadd(u, v);
        cf d = csub(u, v);
        r[b + 3] = { (float)(-SGN) * d.im, (float)SGN * d.re };  // d * (0,SGN)
    }
#pragma unroll
    for (int b = 0; b < 16; b += 2) {
        cf u = r[b], v = r[b + 1];
        r[b] = cadd(u, v); r[b + 1] = csub(u, v);
    }
}

// 8-point DFT, natural in, bit-reversed out: R[k] = r[BR3[k]].
template <int SGN>
__device__ __forceinline__ void dft8(cf* r) {
    const float C8[4] = {1.f, 0.70710678119f, 0.f, -0.70710678119f};
    const float S8[4] = {0.f, 0.70710678119f, 1.f, 0.70710678119f};
#pragma unroll
    for (int j = 0; j < 4; j++) {
        cf u = r[j], v = r[j + 4];
        r[j] = cadd(u, v);
        cf d = csub(u, v);
        cf w = { C8[j], (float)SGN * S8[j] };
        r[j + 4] = cmul(d, w);
    }
#pragma unroll
    for (int b = 0; b < 8; b += 4) {
        cf u = r[b], v = r[b + 2];
        r[b] = cadd(u, v); r[b + 2] = csub(u, v);
        u = r[b + 1]; v = r[b + 3];
        r[b + 1] = cadd(u, v);
        cf d = csub(u, v);
        r[b + 3] = { (float)(-SGN) * d.im, (float)SGN * d.re };
    }
#pragma unroll
    for (int b = 0; b < 8; b += 2) {
        cf u = r[b], v = r[b + 1];
        r[b] = cadd(u, v); r[b + 1] = csub(u, v);
    }
}

// 128-pt FFT "A": input natural ownership r[j] = x[8j+t]; output
// o[8d+k2] = X[t + 8d + 16*k2]. One LDS exchange (region: base + slot*stride).
template <int SGN>
__device__ __forceinline__ void fft128A(cf* r, cf* o, int t,
                                        float* Mre, float* Mim, int base, int stride) {
    dft16<SGN>(r);
    float sv, cv;
    __sincosf(6.283185307179586f * (float)t * (1.0f / 128.0f), &sv, &cv);
    cf w = { cv, (float)SGN * sv };
    cf wp = w;
#pragma unroll
    for (int k = 1; k < 16; k++) {          // k=0 twiddle is 1
        int p = BR4[k];
        r[p] = cmul(r[p], wp);
        wp = cmul(wp, w);
    }
#pragma unroll
    for (int k = 0; k < 16; k++) {
        int slot = 8 * k + (t ^ (k & 7));
        int a = base + slot * stride;
        Mre[a] = r[BR4[k]].re;
        Mim[a] = r[BR4[k]].im;
    }
    __syncthreads();
    cf s0[8], s1[8];
#pragma unroll
    for (int n = 0; n < 8; n++) {
        int a0 = base + (8 * t + (n ^ t)) * stride;
        int a1 = base + (8 * t + 64 + (n ^ t)) * stride;
        s0[n] = { Mre[a0], Mim[a0] };
        s1[n] = { Mre[a1], Mim[a1] };
    }
    dft8<SGN>(s0);
    dft8<SGN>(s1);
#pragma unroll
    for (int k2 = 0; k2 < 8; k2++) {
        o[k2]     = s0[BR3[k2]];
        o[8 + k2] = s1[BR3[k2]];
    }
}

// 128-pt FFT "B": input A-ownership r[8d+k2] = Y[t + 8d + 16*k2]; output
// natural ownership o[m1] = z[8*m1 + t]. One LDS exchange.
template <int SGN>
__device__ __forceinline__ void fft128B(cf* r, cf* o, int t,
                                        float* Mre, float* Mim, int base, int stride) {
    dft8<SGN>(r);       // C[t][mu]   at r[BR3[mu]]
    dft8<SGN>(r + 8);   // C[t+8][mu] at r[8+BR3[mu]]
    float sv, cv;
    __sincosf(6.283185307179586f * (float)t * (1.0f / 128.0f), &sv, &cv);
    cf w0 = { cv, (float)SGN * sv };                               // e^{SGN 2pi i t/128}
    const cf e8 = { 0.92387953251f, (float)SGN * 0.38268343236f }; // e^{SGN 2pi i 8/128}
    cf w1 = cmul(w0, e8);
    cf wp0 = w0, wp1 = w1;
#pragma unroll
    for (int mu = 1; mu < 8; mu++) {        // mu=0 twiddle is 1
        r[BR3[mu]]     = cmul(r[BR3[mu]], wp0);
        r[8 + BR3[mu]] = cmul(r[8 + BR3[mu]], wp1);
        wp0 = cmul(wp0, w0);
        wp1 = cmul(wp1, w1);
    }
#pragma unroll
    for (int mu = 0; mu < 8; mu++) {
        int aA = base + (16 * mu + (t ^ mu)) * stride;
        int aB = base + (16 * mu + ((t ^ mu) + 8)) * stride;   // (t+8)^mu = (t^mu)+8
        Mre[aA] = r[BR3[mu]].re;     Mim[aA] = r[BR3[mu]].im;
        Mre[aB] = r[8 + BR3[mu]].re; Mim[aB] = r[8 + BR3[mu]].im;
    }
    __syncthreads();
    cf q[16];
#pragma unroll
    for (int k = 0; k < 16; k++) {
        int a = base + (16 * t + (k ^ t)) * stride;
        q[k] = { Mre[a], Mim[a] };
    }
    dft16<SGN>(q);       // z[t + 8*m1] = q[BR4[m1]]
#pragma unroll
    for (int m1 = 0; m1 < 16; m1++) o[m1] = q[BR4[m1]];
}

__global__ __launch_bounds__(1024) void operators_52261162057769_kernel(
        const float* __restrict__ x, const float* __restrict__ df,
        const float* __restrict__ d2f, float* __restrict__ out,
        long outn, int nch) {
    extern __shared__ float lds[];
    float* Mre = lds;
    float* Mim = lds + 128 * LSTR;

    const int tid = threadIdx.x;
    const int g = tid >> 3;     // row (R-phases) / column (C-phase) id
    const int t = tid & 7;      // lane within 8-thread FFT group
    const int im = blockIdx.x;
    const int ch = im % nch;
    const long base = (long)im * 16384L;

    // per-channel params (uniform across block)
    const float df0 = df[2 * ch], df1 = df[2 * ch + 1];
    const float ea = expf(df0);
    const cf dfc = { ea * cosf(df1), ea * sinf(df1) };
    const cf d2fc = { d2f[2 * ch], d2f[2 * ch + 1] };
    const cf df2 = cmul(dfc, dfc);
    const float df2m = 1.0f / (df2.re * df2.re + df2.im * df2.im);
    const cf inv_df2 = { df2.re * df2m, -df2.im * df2m };   // 1/dfc^2

    cf r[16], o[16];

    // ---- Phase R1: forward FFT along rows (axis 1) -> H in LDS ----
#pragma unroll
    for (int j = 0; j < 16; j++) {
        r[j].re = x[base + g * 128 + 8 * j + t];
        r[j].im = 0.f;
    }
    fft128A<-1>(r, o, t, Mre, Mim, g * LSTR, 1);
#pragma unroll
    for (int i = 0; i < 16; i++) {
        int col = t + 8 * (i >> 3) + 16 * (i & 7);
        Mre[g * LSTR + col] = o[i].re;
        Mim[g * LSTR + col] = o[i].im;
    }
    __syncthreads();

    // ---- Phase C: per column c=g: fwd FFT (axis 0), multiply by W, W^2,
    //      two inverse FFTs (axis 0). B1 -> LDS, B2 stays in registers. ----
    const int c = g;
#pragma unroll
    for (int j = 0; j < 16; j++) {
        int a = (8 * j + t) * LSTR + c;
        r[j] = { Mre[a], Mim[a] };
    }
    fft128A<-1>(r, o, t, Mre, Mim, c, LSTR);

    const float kc = (c < 64) ? (float)c : (float)(c - 128);
    cf g1[16], g2[16];
#pragma unroll
    for (int i = 0; i < 16; i++) {
        int d = i >> 3, k2 = i & 7;
        int k = t + 8 * d + 16 * k2;
        float kr = (k2 < 4) ? (float)k : (float)(k - 128);  // k>=64 <=> k2>=4
        cf W = { -kc, kr };                                 // i*k_r - k_c
        cf P = cmul(W, o[i]);
        cf Q = cmul(W, P);
        const float invZ = 1.0f / 16384.0f;                 // ifft2 normalization
        g1[i] = { P.re * invZ, P.im * invZ };
        g2[i] = { Q.re * invZ, Q.im * invZ };
    }
    cf b2[16];
    fft128B<1>(g2, b2, t, Mre, Mim, c, LSTR);   // B2 = IFFT0(W^2 F) (regs)
    {
        cf b1[16];
        fft128B<1>(g1, b1, t, Mre, Mim, c, LSTR);
#pragma unroll
        for (int m1 = 0; m1 < 16; m1++) {
            int a = (8 * m1 + t) * LSTR + c;
            Mre[a] = b1[m1].re; Mim[a] = b1[m1].im;
        }
    }
    __syncthreads();

    // ---- Phase R2a: inverse FFT along rows of B1 -> dx0; outputs 0..2 ----
#pragma unroll
    for (int j = 0; j < 16; j++) {
        int a = g * LSTR + 8 * j + t;
        r[j] = { Mre[a], Mim[a] };
    }
    cf dx[16];
    fft128A<1>(r, dx, t, Mre, Mim, g * LSTR, 1);

    float* out_h  = out;
    float* out_la = out + outn;
    float* out_ph = out + 2 * outn;
#pragma unroll
    for (int i = 0; i < 16; i++) {
        int col = t + 8 * (i >> 3) + 16 * (i & 7);
        long idx = base + g * 128 + col;
        float xr = dx[i].re, xi = dx[i].im;
        float h = xr * xr + xi * xi;
        out_h[idx] = h;
        bool valid = sqrtf(h) >= 0.001f;
        float sxr = valid ? xr : 1.f;
        float sxi = valid ? xi : 0.f;
        float hs  = valid ? h : 1.f;
        float ih  = 1.f / hs;
        // a2 = dfc * conj(dxs) / |dxs|^2
        float a2r = (dfc.re * sxr + dfc.im * sxi) * ih;
        float a2i = (dfc.im * sxr - dfc.re * sxi) * ih;
        float la = 0.5f * __logf(a2r * a2r + a2i * a2i);
        la = fminf(fmaxf(la, -3.f), 3.f);
        out_la[idx] = valid ? la : 0.f;
        float ph = atan2f(a2i, a2r);
        out_ph[idx] = valid ? ph : 0.f;
    }
    __syncthreads();

    // ---- swap: B2 registers -> LDS (natural layout) ----
#pragma unroll
    for (int m1 = 0; m1 < 16; m1++) {
        int a = (8 * m1 + t) * LSTR + c;
        Mre[a] = b2[m1].re; Mim[a] = b2[m1].im;
    }
    __syncthreads();

    // ---- Phase R2b: inverse FFT along rows of B2 -> d2x0; outputs 3..4 ----
#pragma unroll
    for (int j = 0; j < 16; j++) {
        int a = g * LSTR + 8 * j + t;
        r[j] = { Mre[a], Mim[a] };
    }
    cf dy[16];
    fft128A<1>(r, dy, t, Mre, Mim, g * LSTR, 1);

    float* out_lt = out + 3 * outn;
    float* out_ps = out + 4 * outn;
#pragma unroll
    for (int i = 0; i < 16; i++) {
        int col = t + 8 * (i >> 3) + 16 * (i & 7);
        long idx = base + g * 128 + col;
        float xr = dx[i].re, xi = dx[i].im;
        float yr = dy[i].re, yi = dy[i].im;
        float h = xr * xr + xi * xi;
        bool valid = sqrtf(h) >= 0.001f;
        float sxr = valid ? xr : 1.f;
        float sxi = valid ? xi : 0.f;
        float hs  = valid ? h : 1.f;
        float ih  = 1.f / hs;
        // w2 = dxs^2
        float w2r = sxr * sxr - sxi * sxi;
        float w2i = 2.f * sxr * sxi;
        // an = 0.5*(d2x0 - d2fc*w2/dfc^2) * dfc * conj(w2) / hs^2
        cf t1 = cmul(d2fc, { w2r, w2i });
        cf u  = cmul(t1, inv_df2);
        cf v  = { yr - u.re, yi - u.im };
        cf t2 = cmul(v, dfc);
        cf t3 = cmul(t2, { w2r, -w2i });
        float s = 0.5f * ih * ih;
        float anr = t3.re * s, ani = t3.im * s;
        float m2 = anr * anr + ani * ani;
        bool tm = valid && (sqrtf(m2) >= 0.001f);
        float lt = 0.5f * __logf(m2);
        lt = fminf(fmaxf(lt, -2.5902671654f), 3.f);
        out_lt[idx] = tm ? lt : -6.9077552790f;
        float ps = atan2f(ani, anr);
        out_ps[idx] = tm ? ps : 0.f;
    }
}

extern "C" void kernel_launch(void* const* d_in, const int* in_sizes, int n_in,
                              void* d_out, int out_size, void* d_ws, size_t ws_size,
                              hipStream_t stream) {
    const float* x   = (const float*)d_in[0];
    const float* df  = (const float*)d_in[1];
    const float* d2f = (const float*)d_in[2];
    float* out = (float*)d_out;

    const int n_img = in_sizes[0] / 16384;       // b*C = 1024
    const int nch   = in_sizes[1] / 2;           // C = 64
    const long outn = (long)out_size / 5;

    // >64KB dynamic LDS needs the attribute; host-side, graph-capture safe.
    hipFuncSetAttribute((const void*)operators_52261162057769_kernel,
                        hipFuncAttributeMaxDynamicSharedMemorySize, SHBYTES);

    operators_52261162057769_kernel<<<dim3(n_img), dim3(1024), SHBYTES, stream>>>(
        x, df, d2f, out, outn, nch);
}

// Round 2
// 851.027 us; speedup vs baseline: 1.0017x; 1.0017x over previous
//
#include <hip/hip_runtime.h>
#include <math.h>

// Fused spectral Wirtinger-derivative kernel.
// One 1024-thread block per (b,C) image; whole 128x128 complex image in LDS.
// Each 128-point FFT: 8 threads x 16 register points, 16x8 Cooley-Tukey,
// single LDS exchange per 1-D transform. XOR-swizzled exchange slots keep
// LDS bank conflicts <=2-way (free on gfx950).
//
// __launch_bounds__(1024, 4): LDS (135KB) limits us to 1 block/CU anyway,
// so allow the full 128 VGPRs (4 waves/EU). R0's default capped VGPRs at 64
// and spilled ~1.2GB/dispatch to scratch (FETCH 548MB vs 64MB ideal).

#define LSTR 132                 // LDS row stride in floats (+4 pad: 2-way banks)
#define SHBYTES (2 * 128 * LSTR * 4)

struct cf { float re, im; };
__device__ __forceinline__ cf cmul(cf a, cf b) {
    return { a.re * b.re - a.im * b.im, a.re * b.im + a.im * b.re };
}
__device__ __forceinline__ cf cadd(cf a, cf b) { return { a.re + b.re, a.im + b.im }; }
__device__ __forceinline__ cf csub(cf a, cf b) { return { a.re - b.re, a.im - b.im }; }

// bit-reversal tables (involutions)
__device__ constexpr int BR4[16] = {0,8,4,12,2,10,6,14,1,9,5,13,3,11,7,15};
__device__ constexpr int BR3[8]  = {0,4,2,6,1,5,3,7};

// 16-point DFT, radix-2 DIF, natural in, bit-reversed out: R[k] = r[BR4[k]].
// R[k] = sum_j r[j] e^{SGN*2pi i jk/16}
template <int SGN>
__device__ __forceinline__ void dft16(cf* r) {
    const float C16[8] = {1.f, 0.92387953251f, 0.70710678119f, 0.38268343236f,
                          0.f, -0.38268343236f, -0.70710678119f, -0.92387953251f};
    const float S16[8] = {0.f, 0.38268343236f, 0.70710678119f, 0.92387953251f,
                          1.f, 0.92387953251f, 0.70710678119f, 0.38268343236f};
    const float C8[4] = {1.f, 0.70710678119f, 0.f, -0.70710678119f};
    const float S8[4] = {0.f, 0.70710678119f, 1.f, 0.70710678119f};
#pragma unroll
    for (int j = 0; j < 8; j++) {
        cf u = r[j], v = r[j + 8];
        r[j] = cadd(u, v);
        cf d = csub(u, v);
        cf w = { C16[j], (float)SGN * S16[j] };
        r[j + 8] = cmul(d, w);
    }
#pragma unroll
    for (int b = 0; b < 16; b += 8)
#pragma unroll
        for (int j = 0; j < 4; j++) {
            cf u = r[b + j], v = r[b + j + 4];
            r[b + j] = cadd(u, v);
            cf d = csub(u, v);
            cf w = { C8[j], (float)SGN * S8[j] };
            r[b + j + 4] = cmul(d, w);
        }
#pragma unroll
    for (int b = 0; b < 16; b += 4) {
        cf u = r[b], v = r[b + 2];
        r[b] = cadd(u, v); r[b + 2] = csub(u, v);
        u = r[b + 1]; v = r[b + 3];
        r[b + 1] = cadd(u, v);
        cf d = csub(u, v);
        r[b + 3] = { (float)(-SGN) * d.im, (float)SGN * d.re };  // d * (0,SGN)
    }
#pragma unroll
    for (int b = 0; b < 16; b += 2) {
        cf u = r[b], v = r[b + 1];
        r[b] = cadd(u, v); r[b + 1] = csub(u, v);
    }
}

// 8-point DFT, natural in, bit-reversed out: R[k] = r[BR3[k]].
template <int SGN>
__device__ __forceinline__ void dft8(cf* r) {
    const float C8[4] = {1.f, 0.70710678119f, 0.f, -0.70710678119f};
    const float S8[4] = {0.f, 0.70710678119f, 1.f, 0.70710678119f};
#pragma unroll
    for (int j = 0; j < 4; j++) {
        cf u = r[j], v = r[j + 4];
        r[j] = cadd(u, v);
        cf d = csub(u, v);
        cf w = { C8[j], (float)SGN * S8[j] };
        r[j + 4] = cmul(d, w);
    }
#pragma unroll
    for (int b = 0; b < 8; b += 4) {
        cf u = r[b], v = r[b + 2];
        r[b] = cadd(u, v); r[b + 2] = csub(u, v);
        u = r[b + 1]; v = r[b + 3];
        r[b + 1] = cadd(u, v);
        cf d = csub(u, v);
        r[b + 3] = { (float)(-SGN) * d.im, (float)SGN * d.re };
    }
#pragma unroll
    for (int b = 0; b < 8; b += 2) {
        cf u = r[b], v = r[b + 1];
        r[b] = cadd(u, v); r[b + 1] = csub(u, v);
    }
}

// 128-pt FFT "A": input natural ownership r[j] = x[8j+t]; output
// o[8d+k2] = X[t + 8d + 16*k2]. One LDS exchange (region: base + slot*stride).
template <int SGN>
__device__ __forceinline__ void fft128A(cf* r, cf* o, int t,
                                        float* Mre, float* Mim, int base, int stride) {
    dft16<SGN>(r);
    float sv, cv;
    __sincosf(6.283185307179586f * (float)t * (1.0f / 128.0f), &sv, &cv);
    cf w = { cv, (float)SGN * sv };
    cf wp = w;
#pragma unroll
    for (int k = 1; k < 16; k++) {          // k=0 twiddle is 1
        int p = BR4[k];
        r[p] = cmul(r[p], wp);
        wp = cmul(wp, w);
    }
#pragma unroll
    for (int k = 0; k < 16; k++) {
        int slot = 8 * k + (t ^ (k & 7));
        int a = base + slot * stride;
        Mre[a] = r[BR4[k]].re;
        Mim[a] = r[BR4[k]].im;
    }
    __syncthreads();
    cf s0[8], s1[8];
#pragma unroll
    for (int n = 0; n < 8; n++) {
        int a0 = base + (8 * t + (n ^ t)) * stride;
        int a1 = base + (8 * t + 64 + (n ^ t)) * stride;
        s0[n] = { Mre[a0], Mim[a0] };
        s1[n] = { Mre[a1], Mim[a1] };
    }
    dft8<SGN>(s0);
    dft8<SGN>(s1);
#pragma unroll
    for (int k2 = 0; k2 < 8; k2++) {
        o[k2]     = s0[BR3[k2]];
        o[8 + k2] = s1[BR3[k2]];
    }
}

// 128-pt FFT "B": input A-ownership r[8d+k2] = Y[t + 8d + 16*k2]; output
// natural ownership o[m1] = z[8*m1 + t]. One LDS exchange.
template <int SGN>
__device__ __forceinline__ void fft128B(cf* r, cf* o, int t,
                                        float* Mre, float* Mim, int base, int stride) {
    dft8<SGN>(r);       // C[t][mu]   at r[BR3[mu]]
    dft8<SGN>(r + 8);   // C[t+8][mu] at r[8+BR3[mu]]
    float sv, cv;
    __sincosf(6.283185307179586f * (float)t * (1.0f / 128.0f), &sv, &cv);
    cf w0 = { cv, (float)SGN * sv };                               // e^{SGN 2pi i t/128}
    const cf e8 = { 0.92387953251f, (float)SGN * 0.38268343236f }; // e^{SGN 2pi i 8/128}
    cf w1 = cmul(w0, e8);
    cf wp0 = w0, wp1 = w1;
#pragma unroll
    for (int mu = 1; mu < 8; mu++) {        // mu=0 twiddle is 1
        r[BR3[mu]]     = cmul(r[BR3[mu]], wp0);
        r[8 + BR3[mu]] = cmul(r[8 + BR3[mu]], wp1);
        wp0 = cmul(wp0, w0);
        wp1 = cmul(wp1, w1);
    }
#pragma unroll
    for (int mu = 0; mu < 8; mu++) {
        int aA = base + (16 * mu + (t ^ mu)) * stride;
        int aB = base + (16 * mu + ((t ^ mu) + 8)) * stride;   // (t+8)^mu = (t^mu)+8
        Mre[aA] = r[BR3[mu]].re;     Mim[aA] = r[BR3[mu]].im;
        Mre[aB] = r[8 + BR3[mu]].re; Mim[aB] = r[8 + BR3[mu]].im;
    }
    __syncthreads();
    cf q[16];
#pragma unroll
    for (int k = 0; k < 16; k++) {
        int a = base + (16 * t + (k ^ t)) * stride;
        q[k] = { Mre[a], Mim[a] };
    }
    dft16<SGN>(q);       // z[t + 8*m1] = q[BR4[m1]]
#pragma unroll
    for (int m1 = 0; m1 < 16; m1++) o[m1] = q[BR4[m1]];
}

__global__ __launch_bounds__(1024, 4) void operators_52261162057769_kernel(
        const float* __restrict__ x, const float* __restrict__ df,
        const float* __restrict__ d2f, float* __restrict__ out,
        long outn, int nch) {
    extern __shared__ float lds[];
    float* Mre = lds;
    float* Mim = lds + 128 * LSTR;

    const int tid = threadIdx.x;
    const int g = tid >> 3;     // row (R-phases) / column (C-phase) id
    const int t = tid & 7;      // lane within 8-thread FFT group
    const int im = blockIdx.x;
    const int ch = im % nch;
    const long base = (long)im * 16384L;

    // per-channel params (uniform across block)
    const float df0 = df[2 * ch], df1 = df[2 * ch + 1];
    const float ea = expf(df0);
    const cf dfc = { ea * cosf(df1), ea * sinf(df1) };
    const cf d2fc = { d2f[2 * ch], d2f[2 * ch + 1] };
    const cf df2 = cmul(dfc, dfc);
    const float df2m = 1.0f / (df2.re * df2.re + df2.im * df2.im);
    const cf inv_df2 = { df2.re * df2m, -df2.im * df2m };   // 1/dfc^2

    cf r[16], o[16];

    // ---- Phase R1: forward FFT along rows (axis 1) -> H in LDS ----
#pragma unroll
    for (int j = 0; j < 16; j++) {
        r[j].re = x[base + g * 128 + 8 * j + t];
        r[j].im = 0.f;
    }
    fft128A<-1>(r, o, t, Mre, Mim, g * LSTR, 1);
#pragma unroll
    for (int i = 0; i < 16; i++) {
        int col = t + 8 * (i >> 3) + 16 * (i & 7);
        Mre[g * LSTR + col] = o[i].re;
        Mim[g * LSTR + col] = o[i].im;
    }
    __syncthreads();

    // ---- Phase C: per column c=g: fwd FFT (axis 0), multiply by W, W^2,
    //      two inverse FFTs (axis 0). B1 -> LDS, B2 stays in registers. ----
    const int c = g;
#pragma unroll
    for (int j = 0; j < 16; j++) {
        int a = (8 * j + t) * LSTR + c;
        r[j] = { Mre[a], Mim[a] };
    }
    fft128A<-1>(r, o, t, Mre, Mim, c, LSTR);

    const float kc = (c < 64) ? (float)c : (float)(c - 128);
    cf g1[16], g2[16];
#pragma unroll
    for (int i = 0; i < 16; i++) {
        int d = i >> 3, k2 = i & 7;
        int k = t + 8 * d + 16 * k2;
        float kr = (k2 < 4) ? (float)k : (float)(k - 128);  // k>=64 <=> k2>=4
        cf W = { -kc, kr };                                 // i*k_r - k_c
        cf P = cmul(W, o[i]);
        cf Q = cmul(W, P);
        const float invZ = 1.0f / 16384.0f;                 // ifft2 normalization
        g1[i] = { P.re * invZ, P.im * invZ };
        g2[i] = { Q.re * invZ, Q.im * invZ };
    }
    cf b2[16];
    fft128B<1>(g2, b2, t, Mre, Mim, c, LSTR);   // B2 = IFFT0(W^2 F) (regs)
    {
        cf b1[16];
        fft128B<1>(g1, b1, t, Mre, Mim, c, LSTR);
#pragma unroll
        for (int m1 = 0; m1 < 16; m1++) {
            int a = (8 * m1 + t) * LSTR + c;
            Mre[a] = b1[m1].re; Mim[a] = b1[m1].im;
        }
    }
    __syncthreads();

    // ---- Phase R2a: inverse FFT along rows of B1 -> dx0; outputs 0..2 ----
#pragma unroll
    for (int j = 0; j < 16; j++) {
        int a = g * LSTR + 8 * j + t;
        r[j] = { Mre[a], Mim[a] };
    }
    cf dx[16];
    fft128A<1>(r, dx, t, Mre, Mim, g * LSTR, 1);

    float* out_h  = out;
    float* out_la = out + outn;
    float* out_ph = out + 2 * outn;
#pragma unroll
    for (int i = 0; i < 16; i++) {
        int col = t + 8 * (i >> 3) + 16 * (i & 7);
        long idx = base + g * 128 + col;
        float xr = dx[i].re, xi = dx[i].im;
        float h = xr * xr + xi * xi;
        out_h[idx] = h;
        bool valid = sqrtf(h) >= 0.001f;
        float sxr = valid ? xr : 1.f;
        float sxi = valid ? xi : 0.f;
        float hs  = valid ? h : 1.f;
        float ih  = 1.f / hs;
        // a2 = dfc * conj(dxs) / |dxs|^2
        float a2r = (dfc.re * sxr + dfc.im * sxi) * ih;
        float a2i = (dfc.im * sxr - dfc.re * sxi) * ih;
        float la = 0.5f * __logf(a2r * a2r + a2i * a2i);
        la = fminf(fmaxf(la, -3.f), 3.f);
        out_la[idx] = valid ? la : 0.f;
        float ph = atan2f(a2i, a2r);
        out_ph[idx] = valid ? ph : 0.f;
    }
    __syncthreads();

    // ---- swap: B2 registers -> LDS (natural layout) ----
#pragma unroll
    for (int m1 = 0; m1 < 16; m1++) {
        int a = (8 * m1 + t) * LSTR + c;
        Mre[a] = b2[m1].re; Mim[a] = b2[m1].im;
    }
    __syncthreads();

    // ---- Phase R2b: inverse FFT along rows of B2 -> d2x0; outputs 3..4 ----
#pragma unroll
    for (int j = 0; j < 16; j++) {
        int a = g * LSTR + 8 * j + t;
        r[j] = { Mre[a], Mim[a] };
    }
    cf dy[16];
    fft128A<1>(r, dy, t, Mre, Mim, g * LSTR, 1);

    float* out_lt = out + 3 * outn;
    float* out_ps = out + 4 * outn;
#pragma unroll
    for (int i = 0; i < 16; i++) {
        int col = t + 8 * (i >> 3) + 16 * (i & 7);
        long idx = base + g * 128 + col;
        float xr = dx[i].re, xi = dx[i].im;
        float yr = dy[i].re, yi = dy[i].im;
        float h = xr * xr + xi * xi;
        bool valid = sqrtf(h) >= 0.001f;
        float sxr = valid ? xr : 1.f;
        float sxi = valid ? xi : 0.f;
        float hs  = valid ? h : 1.f;
        float ih  = 1.f / hs;
        // w2 = dxs^2
        float w2r = sxr * sxr - sxi * sxi;
        float w2i = 2.f * sxr * sxi;
        // an = 0.5*(d2x0 - d2fc*w2/dfc^2) * dfc * conj(w2) / hs^2
        cf t1 = cmul(d2fc, { w2r, w2i });
        cf u  = cmul(t1, inv_df2);
        cf v  = { yr - u.re, yi - u.im };
        cf t2 = cmul(v, dfc);
        cf t3 = cmul(t2, { w2r, -w2i });
        float s = 0.5f * ih * ih;
        float anr = t3.re * s, ani = t3.im * s;
        float m2 = anr * anr + ani * ani;
        bool tm = valid && (sqrtf(m2) >= 0.001f);
        float lt = 0.5f * __logf(m2);
        lt = fminf(fmaxf(lt, -2.5902671654f), 3.f);
        out_lt[idx] = tm ? lt : -6.9077552790f;
        float ps = atan2f(ani, anr);
        out_ps[idx] = tm ? ps : 0.f;
    }
}

extern "C" void kernel_launch(void* const* d_in, const int* in_sizes, int n_in,
                              void* d_out, int out_size, void* d_ws, size_t ws_size,
                              hipStream_t stream) {
    const float* x   = (const float*)d_in[0];
    const float* df  = (const float*)d_in[1];
    const float* d2f = (const float*)d_in[2];
    float* out = (float*)d_out;

    const int n_img = in_sizes[0] / 16384;       // b*C = 1024
    const int nch   = in_sizes[1] / 2;           // C = 64
    const long outn = (long)out_size / 5;

    // >64KB dynamic LDS needs the attribute; host-side, graph-capture safe.
    hipFuncSetAttribute((const void*)operators_52261162057769_kernel,
                        hipFuncAttributeMaxDynamicSharedMemorySize, SHBYTES);

    operators_52261162057769_kernel<<<dim3(n_img), dim3(1024), SHBYTES, stream>>>(
        x, df, d2f, out, outn, nch);
}